// Round 17
// baseline (2033.756 us; speedup 1.0000x reference)
//
#include <hip/hip_runtime.h>
#include <math.h>

// ---------- types / helpers ----------
typedef unsigned short u16;
typedef unsigned int   u32;
typedef u16   u16x8 __attribute__((ext_vector_type(8)));
typedef u16   u16x4 __attribute__((ext_vector_type(4)));
typedef short s16x8 __attribute__((ext_vector_type(8)));
typedef float f32x4 __attribute__((ext_vector_type(4)));

#define DEVFN static __device__ __forceinline__
#define GLOBAL_AS __attribute__((address_space(1)))
#define LDS_AS    __attribute__((address_space(3)))

constexpr int Bb = 16, Hh = 48, Ww = 48, Dd = 384;
constexpr int Nn = Hh * Ww;          // 2304 tokens per image
constexpr int NT = Bb * Nn;          // 36864 total tokens
constexpr int NH = 8, DHd = 48;      // heads, head dim
constexpr int INNER = NH * DHd;      // 384
constexpr int QC = 3 * INNER;        // 1152
constexpr int MF = 1536;
constexpr int DEPTH = 4;
constexpr int NCH = 6;               // n-split chunks for k_sim

DEVFN float bf2f(u16 u) { return __uint_as_float(((u32)u) << 16); }
DEVFN u16   f2bu(float f) { u32 x = __float_as_uint(f); return (u16)((x + 0x7FFFu + ((x >> 16) & 1u)) >> 16); }
DEVFN float geluf(float x) { return 0.5f * x * (1.0f + erff(x * 0.70710678118654752440f)); }

DEVFN void gload16(const u16* g, u16* lds_base) {
    __builtin_amdgcn_global_load_lds((const GLOBAL_AS void*)g, (LDS_AS void*)lds_base, 16, 0, 0);
}

// ---------- fp32 -> fp32 copy (seed residual stream in d_out) ----------
__global__ void k_copy(const float* __restrict__ in, float* __restrict__ X) {
    size_t i0 = ((size_t)blockIdx.x * 256 + threadIdx.x) * 4;
    *(f32x4*)(X + i0) = *(const f32x4*)(in + i0);
}

// ---------- transpose + fp32->bf16: in [K][N] f32 -> out [N][K] bf16 ----------
__global__ __launch_bounds__(256) void k_trb(const float* __restrict__ in, u16* __restrict__ out,
                                             int K, int N) {
    __shared__ float tile[64][65];
    in  += (size_t)blockIdx.z * K * N;
    out += (size_t)blockIdx.z * K * N;
    int k0 = blockIdx.y * 64, n0 = blockIdx.x * 64;
    int t = threadIdx.x;
    int r = t >> 4, c = (t & 15) * 4;
#pragma unroll
    for (int j = 0; j < 4; j++) {
        f32x4 v = *(const f32x4*)&in[(size_t)(k0 + r + j * 16) * N + n0 + c];
        tile[r + j * 16][c] = v[0]; tile[r + j * 16][c + 1] = v[1];
        tile[r + j * 16][c + 2] = v[2]; tile[r + j * 16][c + 3] = v[3];
    }
    __syncthreads();
#pragma unroll
    for (int j = 0; j < 4; j++) {
        u16x4 o;
#pragma unroll
        for (int i = 0; i < 4; i++) o[i] = f2bu(tile[c + i][r + j * 16]);
        *(u16x4*)&out[(size_t)(n0 + r + j * 16) * K + k0 + c] = o;
    }
}

// ---------- LayerNorm full: X fp32 [NT][384] -> bf16 out ----------
__global__ __launch_bounds__(256) void k_ln(const float* __restrict__ X,
                                            const float* __restrict__ g, const float* __restrict__ bta,
                                            u16* __restrict__ out) {
    int row = blockIdx.x * 4 + (threadIdx.x >> 6);
    int lane = threadIdx.x & 63;
    const float* xr = X + (size_t)row * Dd;
    float v[6]; float s = 0.f, s2 = 0.f;
#pragma unroll
    for (int j = 0; j < 6; j++) { v[j] = xr[lane + 64 * j]; s += v[j]; s2 += v[j] * v[j]; }
#pragma unroll
    for (int off = 32; off >= 1; off >>= 1) { s += __shfl_down(s, off); s2 += __shfl_down(s2, off); }
    s = __shfl(s, 0); s2 = __shfl(s2, 0);
    float m = s * (1.0f / Dd);
    float rstd = 1.0f / sqrtf(s2 * (1.0f / Dd) - m * m + 1e-5f);
    u16* orow = out + (size_t)row * Dd;
#pragma unroll
    for (int j = 0; j < 6; j++) {
        int c = lane + 64 * j;
        orow[c] = f2bu((v[j] - m) * rstd * g[c] + bta[c]);
    }
}

// ---------- MFMA GEMM: C[M,N] = A[M,K](bf16) @ BT[N,K](bf16), fp32 acc ----------
// ROUND-8 EXACT K-LOOP. MODE 0: store bf16. MODE 1: gelu(acc+bias)->bf16.
// MODE 2: X += scale*(acc+bias). MODE 3: MODE 0 + q/k column-ssq -> QP.
// MODE 4: MODE 2 + per-row LN partials -> QP (as LNP) via dead Ts LDS.
// bf16-output modes (0/1/3) stage the output tile through dead Ts LDS and
// store coalesced u16x8 (fixes 2.5x HBM write amplification of 32B segments).
template <int MODE>
__global__ __launch_bounds__(512, 4) void k_mgemm(const u16* __restrict__ A, const u16* __restrict__ BT,
                                                  int Kdim, int Ndim,
                                                  const float* __restrict__ bias, const float* __restrict__ scale,
                                                  float* __restrict__ Xres, u16* __restrict__ Out,
                                                  float* __restrict__ QP) {
    __shared__ __align__(16) u16 Ts[3][24 * 512];
    __shared__ float QS[4][128];                 // MODE 3 cross-wave ssq partials
    const int gridX = Ndim >> 7;                 // N / 128
    const int nwg = gridX * (NT >> 8);           // * M/256
    const int cpx = nwg >> 3;
    const int id = blockIdx.x;
    const int id2 = (id & 7) * cpx + (id >> 3);  // bijective when nwg%8==0
    const int n0 = (id2 % gridX) * 128;
    const int m0 = (id2 / gridX) * 256;
    const int t = threadIdx.x;
    const int w = t >> 6, l = t & 63;
    const int wm = w >> 1, wn = w & 1;
    const int lr = l >> 2;                       // row-in-chunk
    const int sc = ((l & 3) ^ (lr & 3)) * 8;     // pre-swizzled source chunk (u16)
    const int fr = l & 15, rq = l >> 4;
    const int c0 = w * 3;                        // this wave's 3 staging chunks

    auto stage = [&](int buf, int k0) {
#pragma unroll
        for (int j = 0; j < 3; j++) {
            const int c = c0 + j;
            const u16* src = (c < 16)
                ? A  + (size_t)(m0 + c * 16 + lr) * Kdim + k0 + sc
                : BT + (size_t)(n0 + (c - 16) * 16 + lr) * Kdim + k0 + sc;
            gload16(src, Ts[buf] + c * 512);
        }
    };

    const int nt = Kdim >> 5;
    stage(0, 0);
    stage(1, 32);

    f32x4 acc[4][4] = {};
    for (int kt = 0; kt < nt; ++kt) {
        if (kt + 1 < nt) {
            asm volatile("s_waitcnt vmcnt(3)" ::: "memory");   // tile kt landed; kt+1 in flight
        } else {
            asm volatile("s_waitcnt vmcnt(0)" ::: "memory");
        }
        __builtin_amdgcn_s_barrier();
        __builtin_amdgcn_sched_barrier(0);
        if (kt + 2 < nt) stage((kt + 2) % 3, (kt + 2) * 32);
        const u16* ts = Ts[kt % 3];
        s16x8 af[4], bf[4];
#pragma unroll
        for (int f = 0; f < 4; f++) {
            const int row = wm * 64 + f * 16 + fr;
            af[f] = *(const s16x8*)&ts[row * 32 + ((rq ^ (fr & 3)) * 8)];
        }
#pragma unroll
        for (int g = 0; g < 4; g++) {
            const int row = wn * 64 + g * 16 + fr;
            bf[g] = *(const s16x8*)&ts[8192 + row * 32 + ((rq ^ (fr & 3)) * 8)];
        }
#pragma unroll
        for (int f = 0; f < 4; f++)
#pragma unroll
            for (int g = 0; g < 4; g++)
                acc[f][g] = __builtin_amdgcn_mfma_f32_16x16x32_bf16(af[f], bf[g], acc[f][g], 0, 0, 0);
    }

    if (MODE == 0 || MODE == 1 || MODE == 3) {
        // ---- staged bf16 store via dead Ts LDS (coalesced u16x8) ----
        float sq[4] = {0.f, 0.f, 0.f, 0.f};
        if (MODE == 3) {
#pragma unroll
            for (int g = 0; g < 4; g++)
#pragma unroll
                for (int f = 0; f < 4; f++)
#pragma unroll
                    for (int r = 0; r < 4; r++) sq[g] += acc[f][g][r] * acc[f][g][r];
        }
        float bv[4];
        if (MODE == 1) {
#pragma unroll
            for (int g = 0; g < 4; g++) bv[g] = bias[n0 + wn * 64 + g * 16 + fr];
        }
        u16* SS = (u16*)&Ts[0][0];   // 128 rows x 136 u16 (padded) = 34 KB
#pragma unroll
        for (int h = 0; h < 2; h++) {
            __syncthreads();
            if ((wm >> 1) == h) {
#pragma unroll
                for (int f = 0; f < 4; f++)
#pragma unroll
                    for (int g = 0; g < 4; g++)
#pragma unroll
                        for (int r = 0; r < 4; r++) {
                            const int row = (wm & 1) * 64 + f * 16 + rq * 4 + r;
                            const int col = wn * 64 + g * 16 + fr;
                            float v = acc[f][g][r];
                            if (MODE == 1) v = geluf(v + bv[g]);
                            SS[row * 136 + col] = f2bu(v);
                        }
            }
            __syncthreads();
#pragma unroll
            for (int i = 0; i < 4; i++) {
                const int chunk = i * 512 + t;           // 2048 chunks = 128 rows x 16
                const int row = chunk >> 4, off = (chunk & 15) * 8;
                *(u16x8*)&Out[(size_t)(m0 + h * 128 + row) * Ndim + n0 + off] =
                    *(const u16x8*)&SS[row * 136 + off];
            }
        }
        if (MODE == 3 && n0 < 768) {   // q,k columns only (block-uniform branch)
#pragma unroll
            for (int g = 0; g < 4; g++) {
                float s2 = sq[g];
                s2 += __shfl_down(s2, 32);
                s2 += __shfl_down(s2, 16);
                if (rq == 0) QS[wm][wn * 64 + g * 16 + fr] = s2;
            }
            __syncthreads();
            if (t < 128) {
                float s = QS[0][t] + QS[1][t] + QS[2][t] + QS[3][t];
                const int b_img = m0 / Nn, mset = (m0 % Nn) >> 8;
                QP[((size_t)(b_img * 9 + mset)) * 768 + n0 + t] = s;
            }
        }
    } else {
        // ---- MODE 2 / MODE 4: fp32 residual update (64B segments, unstaged) ----
        float rs[4][4], rs2[4][4];
        if (MODE == 4) {
#pragma unroll
            for (int f = 0; f < 4; f++)
#pragma unroll
                for (int r = 0; r < 4; r++) { rs[f][r] = 0.f; rs2[f][r] = 0.f; }
        }
#pragma unroll
        for (int g = 0; g < 4; g++) {
            const int n = n0 + wn * 64 + g * 16 + fr;
            float bv = bias[n];
            float sv = scale[n];
#pragma unroll
            for (int f = 0; f < 4; f++) {
                const size_t i0 = (size_t)(m0 + wm * 64 + f * 16 + rq * 4);
#pragma unroll
                for (int r = 0; r < 4; r++) {
                    float v = acc[f][g][r];
                    float* xr = Xres + (i0 + r) * Ndim + n;
                    float xnew = *xr + sv * (v + bv);
                    *xr = xnew;
                    if (MODE == 4) { rs[f][r] += xnew; rs2[f][r] += xnew * xnew; }
                }
            }
        }
        if (MODE == 4) {               // per-row LN partials via dead Ts LDS
            __syncthreads();           // all waves done reading Ts
            float* S = (float*)&Ts[0][0];
            const int col = wn * 16 + fr;
#pragma unroll
            for (int f = 0; f < 4; f++)
#pragma unroll
                for (int r = 0; r < 4; r++) {
                    const int row = wm * 64 + f * 16 + rq * 4 + r;
                    S[row * 32 + col] = rs[f][r];
                    S[8192 + row * 32 + col] = rs2[f][r];
                }
            __syncthreads();
            const int row = t & 255;
            const int comp = t >> 8;   // 0: sum, 1: sumsq
            const float* Sb = S + comp * 8192 + row * 32;
            float s = 0.f;
#pragma unroll
            for (int i = 0; i < 32; i++) s += Sb[i];
            QP[(((size_t)(n0 >> 7)) * NT + (m0 + row)) * 2 + comp] = s;
        }
    }
}

// ---------- finalize inv-norms: sum 9 m-set partials per (b, col<768) ----------
__global__ void k_nrm_fin(const float* __restrict__ QP, float* __restrict__ INVN) {
    int idx = blockIdx.x * 256 + threadIdx.x; // < 16*768
    int b = idx / 768, c = idx - b * 768;
    float s = 0;
#pragma unroll
    for (int ms = 0; ms < 9; ms++) s += QP[((size_t)(b * 9 + ms)) * 768 + c];
    INVN[idx] = 1.0f / fmaxf(sqrtf(s), 1e-12f);
}

// ---------- finalize LN stats from MODE-4 partials: LNS[row] = {m, rstd} ----------
__global__ void k_lnfin(const float* __restrict__ LNP, float* __restrict__ LNS) {
    int row = blockIdx.x * 256 + threadIdx.x;   // NT rows
    float s  = LNP[((size_t)0 * NT + row) * 2]     + LNP[((size_t)1 * NT + row) * 2]     + LNP[((size_t)2 * NT + row) * 2];
    float s2 = LNP[((size_t)0 * NT + row) * 2 + 1] + LNP[((size_t)1 * NT + row) * 2 + 1] + LNP[((size_t)2 * NT + row) * 2 + 1];
    float m = s * (1.0f / Dd);
    float rstd = 1.0f / sqrtf(s2 * (1.0f / Dd) - m * m + 1e-5f);
    LNS[row * 2] = m;
    LNS[row * 2 + 1] = rstd;
}

// ---------- sim partials via MFMA: SIMP[chunk][bh][d][e] over n-chunk ----------
__global__ __launch_bounds__(256) void k_sim(const u16* __restrict__ QKV, float* __restrict__ SIMP) {
    const int bh = blockIdx.x;
    const int b = bh >> 3, h = bh & 7;
    const int chunk = blockIdx.y;
    __shared__ float qt[48][65];
    __shared__ float kt[48][65];
    const int t = threadIdx.x;
    const int w = t >> 6, l = t & 63;
    const int fr = l & 15, rq = l >> 4;
    const int ti0 = w, ti1 = w + 4;              // tile 8 handled by wave 0 only
    f32x4 acc0 = {}, acc1 = {}, acc2 = {};

    auto doTile = [&](int ti, f32x4& a) {
        const int d0 = (ti / 3) * 16, e0 = (ti % 3) * 16;
#pragma unroll
        for (int s = 0; s < 2; s++) {
            const float* qp = &qt[d0 + fr][s * 32 + rq * 8];
            const float* kp = &kt[e0 + fr][s * 32 + rq * 8];
            s16x8 af, bf;
#pragma unroll
            for (int j = 0; j < 8; j++) {
                af[j] = (short)(__float_as_uint(qp[j]) >> 16);   // exact: values are bf16
                bf[j] = (short)(__float_as_uint(kp[j]) >> 16);
            }
            a = __builtin_amdgcn_mfma_f32_16x16x32_bf16(af, bf, a, 0, 0, 0);
        }
    };

    for (int c0 = chunk * (Nn / NCH); c0 < (chunk + 1) * (Nn / NCH); c0 += 64) {
        __syncthreads();
        for (int e = t; e < 48 * 64; e += 256) {
            int r = e / 48, d = e - r * 48;
            const u16* p = QKV + (size_t)(b * Nn + c0 + r) * QC + h * DHd + d;
            qt[d][r] = bf2f(p[0]);
            kt[d][r] = bf2f(p[INNER]);
        }
        __syncthreads();
        doTile(ti0, acc0);
        doTile(ti1, acc1);
        if (w == 0) doTile(8, acc2);
    }

    float* so = SIMP + ((size_t)chunk * (Bb * NH) + bh) * (DHd * DHd);
    auto wr = [&](int ti, const f32x4& a) {
        const int d0 = (ti / 3) * 16, e0 = (ti % 3) * 16;
#pragma unroll
        for (int r = 0; r < 4; r++) so[(d0 + rq * 4 + r) * DHd + e0 + fr] = a[r];
    };
    wr(ti0, acc0);
    wr(ti1, acc1);
    if (w == 0) wr(8, acc2);
}

// ---------- softmax: reduce SIMP chunks, scale, softmax over e -> SIM ----------
__global__ __launch_bounds__(256) void k_smax(const float* __restrict__ SIMP, float* __restrict__ SIM,
                                              const float* __restrict__ INVN, const float* __restrict__ temp) {
    int wid = blockIdx.x * 4 + (threadIdx.x >> 6);
    int lane = threadIdx.x & 63;
    int b = wid / (NH * DHd); int rem = wid - b * NH * DHd; int h = rem / DHd; int d = rem - h * DHd;
    int bh = b * NH + h;
    float et = expf(temp[h]);
    float invq = INVN[b * 768 + h * DHd + d];
    float myv = 0.f, mv = -3.0e38f;
    if (lane < DHd) {
        float s = 0.f;
#pragma unroll
        for (int c = 0; c < NCH; c++)
            s += SIMP[((size_t)c * (Bb * NH) + bh) * (DHd * DHd) + d * DHd + lane];
        myv = s * invq * INVN[b * 768 + 384 + h * DHd + lane] * et;
        mv = myv;
    }
#pragma unroll
    for (int off = 32; off >= 1; off >>= 1) mv = fmaxf(mv, __shfl_down(mv, off));
    mv = __shfl(mv, 0);
    float e = (lane < DHd) ? expf(myv - mv) : 0.f;
    float s = e;
#pragma unroll
    for (int off = 32; off >= 1; off >>= 1) s += __shfl_down(s, off);
    s = __shfl(s, 0);
    if (lane < DHd) SIM[(size_t)bh * (DHd * DHd) + d * DHd + lane] = e / s;
}

// ---------- out[b,n,h*48+d] = sum_e attn[d,e] * v[b,n,h,e]; one row per thread ----------
__global__ __launch_bounds__(256) void k_av(const u16* __restrict__ QKV, const float* __restrict__ SIM,
                                            u16* __restrict__ AOUT) {
    const int bh = blockIdx.x;
    const int b = bh >> 3, h = bh & 7;
    __shared__ __align__(16) float at[48][52];
    const int t = threadIdx.x;
    for (int e = t; e < 48 * 48; e += 256) at[e / 48][e % 48] = SIM[(size_t)bh * (DHd * DHd) + e];
    __syncthreads();
    const int r = blockIdx.y * 256 + t;   // grid.y = 9 -> 2304 rows
    const u16x8* vp = (const u16x8*)(QKV + (size_t)(b * Nn + r) * QC + 2 * INNER + h * DHd);
    f32x4 vv[12];
#pragma unroll
    for (int q8 = 0; q8 < 6; q8++) {
        u16x8 u = vp[q8];
#pragma unroll
        for (int j = 0; j < 8; j++) vv[q8 * 2 + (j >> 2)][j & 3] = bf2f(u[j]);
    }
    u16x8 ob[6];
#pragma unroll
    for (int d = 0; d < 48; d++) {
        f32x4 sv = {0.f, 0.f, 0.f, 0.f};
#pragma unroll
        for (int e4 = 0; e4 < 12; e4++) sv += *(const f32x4*)&at[d][e4 * 4] * vv[e4];
        ob[d >> 3][d & 7] = f2bu(sv[0] + sv[1] + sv[2] + sv[3]);
    }
    u16x8* orow = (u16x8*)(AOUT + (size_t)(b * Nn + r) * Dd + h * DHd);
#pragma unroll
    for (int q8 = 0; q8 < 6; q8++) orow[q8] = ob[q8];
}

// ---------- LPI fused kernel 1: LN-apply + dwconv3x3 + BN partial sums ----------
__global__ __launch_bounds__(384) void k_lpi1(const float* __restrict__ X, const float* __restrict__ LNS,
                                              const float* __restrict__ g, const float* __restrict__ bta,
                                              const float* __restrict__ wgt, const float* __restrict__ cbias,
                                              u16* __restrict__ CF, float* __restrict__ BNP) {
    const int c = threadIdx.x;
    const int by = blockIdx.x;
    const int y = by % Hh, b = by / Hh;
    const int x0 = blockIdx.y * (Ww / 2);
    float w9[9];
#pragma unroll
    for (int j = 0; j < 9; j++) w9[j] = wgt[c * 9 + j];
    const float gc = g[c], bc = bta[c], cb = cbias[c];
    const size_t base = (size_t)b * Nn * Dd;
    const float* lns = LNS + (size_t)b * Nn * 2;

    auto load3 = [&](int xx, float* col) {
        if (xx < 0 || xx >= Ww) { col[0] = col[1] = col[2] = 0.f; return; }
#pragma unroll
        for (int dy = 0; dy < 3; dy++) {
            int yy = y + dy - 1;
            if (yy < 0 || yy >= Hh) { col[dy] = 0.f; }
            else {
                int tok = yy * Ww + xx;
                float m = lns[tok * 2], r = lns[tok * 2 + 1];
                col[dy] = (X[base + (size_t)tok * Dd + c] - m) * r * gc + bc;
            }
        }
    };

    float A[3], B[3], C[3], T[3];
    load3(x0 - 1, A); load3(x0, B); load3(x0 + 1, C);
    float s = 0.f, s2 = 0.f;
    u16* crow = CF + base + ((size_t)y * Ww + x0) * Dd + c;
    for (int x = x0; x < x0 + Ww / 2; x++) {
        load3(x + 2, T);
        float acc = cb;
#pragma unroll
        for (int dy = 0; dy < 3; dy++)
            acc += w9[dy * 3] * A[dy] + w9[dy * 3 + 1] * B[dy] + w9[dy * 3 + 2] * C[dy];
        crow[(size_t)(x - x0) * Dd] = f2bu(acc);
        s += acc; s2 += acc * acc;
#pragma unroll
        for (int dy = 0; dy < 3; dy++) { A[dy] = B[dy]; B[dy] = C[dy]; C[dy] = T[dy]; }
    }
    float* o = BNP + ((size_t)by * 2 + blockIdx.y) * 768;
    o[c] = s; o[384 + c] = s2;
}

// ---------- BN reduce: 1536 partial blocks -> 64 -> fused affine (bnA, bnB) ----------
__global__ __launch_bounds__(384) void k_bnred1(const float* __restrict__ BNP, float* __restrict__ BNQ) {
    int t = threadIdx.x, blk = blockIdx.x;  // 64 blocks, 24 partials each
    float s = 0.f, s2 = 0.f;
    for (int i = blk * 24; i < blk * 24 + 24; i++) { s += BNP[(size_t)i * 768 + t]; s2 += BNP[(size_t)i * 768 + 384 + t]; }
    BNQ[(size_t)blk * 768 + t] = s; BNQ[(size_t)blk * 768 + 384 + t] = s2;
}

__global__ __launch_bounds__(384) void k_bnred2(const float* __restrict__ BNQ,
                                                const float* __restrict__ bng, const float* __restrict__ bnb,
                                                float* __restrict__ BNC) {
    int t = threadIdx.x;
    float s = 0.f, s2 = 0.f;
    for (int i = 0; i < 64; i++) { s += BNQ[(size_t)i * 768 + t]; s2 += BNQ[(size_t)i * 768 + 384 + t]; }
    float m = s / NT;
    float var = s2 / NT - m * m;
    float r = 1.0f / sqrtf(var + 1e-5f);
    BNC[t] = r * bng[t];
    BNC[384 + t] = bnb[t] - m * r * bng[t];
}

// ---------- LPI fused kernel 2: BN+GELU + dwconv3x3 + residual into X ----------
__global__ __launch_bounds__(384) void k_lpi2(const u16* __restrict__ CF, const float* __restrict__ BNC,
                                              const float* __restrict__ wgt, const float* __restrict__ cbias,
                                              const float* __restrict__ scale, float* __restrict__ X) {
    const int c = threadIdx.x;
    const int by = blockIdx.x;
    const int y = by % Hh, b = by / Hh;
    const int x0 = blockIdx.y * (Ww / 2);
    float w9[9];
#pragma unroll
    for (int j = 0; j < 9; j++) w9[j] = wgt[c * 9 + j];
    const float bnA = BNC[c], bnB = BNC[384 + c];
    const float cb = cbias[c], sc = scale[c];
    const size_t base = (size_t)b * Nn * Dd;

    auto load3 = [&](int xx, float* col) {
        if (xx < 0 || xx >= Ww) { col[0] = col[1] = col[2] = 0.f; return; }
#pragma unroll
        for (int dy = 0; dy < 3; dy++) {
            int yy = y + dy - 1;
            if (yy < 0 || yy >= Hh) { col[dy] = 0.f; }
            else {
                int tok = yy * Ww + xx;
                col[dy] = geluf(bf2f(CF[base + (size_t)tok * Dd + c]) * bnA + bnB);
            }
        }
    };

    float A[3], B[3], C[3], T[3];
    load3(x0 - 1, A); load3(x0, B); load3(x0 + 1, C);
    float* xrow = X + base + ((size_t)y * Ww + x0) * Dd + c;
    for (int x = x0; x < x0 + Ww / 2; x++) {
        load3(x + 2, T);
        float acc = cb;
#pragma unroll
        for (int dy = 0; dy < 3; dy++)
            acc += w9[dy * 3] * A[dy] + w9[dy * 3 + 1] * B[dy] + w9[dy * 3 + 2] * C[dy];
        xrow[(size_t)(x - x0) * Dd] += sc * acc;
#pragma unroll
        for (int dy = 0; dy < 3; dy++) { A[dy] = B[dy]; B[dy] = C[dy]; C[dy] = T[dy]; }
    }
}

// ---------- host launch ----------
extern "C" void kernel_launch(void* const* d_in, const int* in_sizes, int n_in,
                              void* d_out, int out_size, void* d_ws, size_t ws_size,
                              hipStream_t stream) {
    const float* x     = (const float*)d_in[0];
    const float* ln1_g = (const float*)d_in[1];
    const float* ln1_b = (const float*)d_in[2];
    const float* w_qkv = (const float*)d_in[3];
    const float* temp  = (const float*)d_in[4];
    const float* w_out = (const float*)d_in[5];
    const float* b_out = (const float*)d_in[6];
    const float* s_att = (const float*)d_in[7];
    const float* lpi_g = (const float*)d_in[8];
    const float* lpi_b = (const float*)d_in[9];
    const float* c1w   = (const float*)d_in[10];
    const float* c1b   = (const float*)d_in[11];
    const float* bng   = (const float*)d_in[12];
    const float* bnb   = (const float*)d_in[13];
    const float* c2w   = (const float*)d_in[14];
    const float* c2b   = (const float*)d_in[15];
    const float* s_lpi = (const float*)d_in[16];
    const float* ff_g  = (const float*)d_in[17];
    const float* ff_b  = (const float*)d_in[18];
    const float* w1    = (const float*)d_in[19];
    const float* b1    = (const float*)d_in[20];
    const float* w2    = (const float*)d_in[21];
    const float* b2    = (const float*)d_in[22];
    const float* s_ff  = (const float*)d_in[23];

    float* X = (float*)d_out;  // residual stream lives in d_out (fp32)

    char* p = (char*)d_ws;
    auto carve = [&](size_t bytes) -> char* { char* r = p; p += (bytes + 255) / 256 * 256; return r; };
    u16*   BIG  = (u16*)  carve((size_t)NT * MF * 2);            // QKV / CF / FF1
    u16*   Hb   = (u16*)  carve((size_t)NT * Dd * 2);            // LN outputs
    float* SIM  = (float*)carve((size_t)Bb * NH * DHd * DHd * 4);
    float* SIMP = (float*)carve((size_t)NCH * Bb * NH * DHd * DHd * 4);
    float* INVN = (float*)carve((size_t)Bb * 768 * 4);
    float* QP   = (float*)carve((size_t)Bb * 9 * 768 * 4);
    float* LNP  = (float*)carve((size_t)3 * NT * 2 * 4);
    float* LNS  = (float*)carve((size_t)NT * 2 * 4);
    float* BNP  = (float*)carve((size_t)1536 * 768 * 4);
    float* BNQ  = (float*)carve((size_t)64 * 768 * 4);
    float* BNC  = (float*)carve((size_t)768 * 4);
    u16*   WQT  = (u16*)  carve((size_t)DEPTH * Dd * QC * 2);    // bf16 transposed weights [N][K]
    u16*   WOT  = (u16*)  carve((size_t)DEPTH * INNER * Dd * 2);
    u16*   W1T  = (u16*)  carve((size_t)DEPTH * Dd * MF * 2);
    u16*   W2T  = (u16*)  carve((size_t)DEPTH * MF * Dd * 2);
    u16*   AO   = BIG + (size_t)NT * QC;   // attention out aliases tail of BIG
    u16*   CF   = BIG;                     // conv1 bf16 out aliases BIG (QKV dead by then)

    k_trb<<<dim3(QC / 64, Dd / 64, DEPTH), 256, 0, stream>>>(w_qkv, WQT, Dd, QC);
    k_trb<<<dim3(Dd / 64, INNER / 64, DEPTH), 256, 0, stream>>>(w_out, WOT, INNER, Dd);
    k_trb<<<dim3(MF / 64, Dd / 64, DEPTH), 256, 0, stream>>>(w1, W1T, Dd, MF);
    k_trb<<<dim3(Dd / 64, MF / 64, DEPTH), 256, 0, stream>>>(w2, W2T, MF, Dd);

    k_copy<<<NT * Dd / 1024, 256, 0, stream>>>(x, X);
    for (int L = 0; L < DEPTH; L++) {
        // ---- XCA ----
        k_ln<<<NT / 4, 256, 0, stream>>>(X, ln1_g + L * Dd, ln1_b + L * Dd, Hb);
        k_mgemm<3><<<(QC / 128) * (NT / 256), 512, 0, stream>>>(Hb, WQT + (size_t)L * Dd * QC, Dd, QC,
                                                                nullptr, nullptr, nullptr, BIG, QP);
        k_nrm_fin<<<Bb * 768 / 256, 256, 0, stream>>>(QP, INVN);
        k_sim<<<dim3(Bb * NH, NCH), 256, 0, stream>>>(BIG, SIMP);
        k_smax<<<Bb * NH * DHd / 4, 256, 0, stream>>>(SIMP, SIM, INVN, temp + L * NH);
        k_av<<<dim3(Bb * NH, Nn / 256), 256, 0, stream>>>(BIG, SIM, AO);
        // attn-out GEMM also emits per-row LN partials (MODE 4) -> LNP
        k_mgemm<4><<<(Dd / 128) * (NT / 256), 512, 0, stream>>>(AO, WOT + (size_t)L * INNER * Dd, INNER, Dd,
                                                                b_out + L * Dd, s_att + L * Dd, X, nullptr, LNP);
        k_lnfin<<<NT / 256, 256, 0, stream>>>(LNP, LNS);
        // ---- LPI (fused) ----
        k_lpi1<<<dim3(Bb * Hh, 2), 384, 0, stream>>>(X, LNS, lpi_g + L * Dd, lpi_b + L * Dd,
                                                     c1w + (size_t)L * Dd * 9, c1b + L * Dd, CF, BNP);
        k_bnred1<<<64, 384, 0, stream>>>(BNP, BNQ);
        k_bnred2<<<1, 384, 0, stream>>>(BNQ, bng + L * Dd, bnb + L * Dd, BNC);
        k_lpi2<<<dim3(Bb * Hh, 2), 384, 0, stream>>>(CF, BNC, c2w + (size_t)L * Dd * 9, c2b + L * Dd,
                                                     s_lpi + L * Dd, X);
        // ---- FF ----
        k_ln<<<NT / 4, 256, 0, stream>>>(X, ff_g + L * Dd, ff_b + L * Dd, Hb);
        k_mgemm<1><<<(MF / 128) * (NT / 256), 512, 0, stream>>>(Hb, W1T + (size_t)L * Dd * MF, Dd, MF,
                                                                b1 + L * MF, nullptr, nullptr, BIG, nullptr);
        k_mgemm<2><<<(Dd / 128) * (NT / 256), 512, 0, stream>>>(BIG, W2T + (size_t)L * MF * Dd, MF, Dd,
                                                                b2 + L * Dd, s_ff + L * Dd, X, nullptr, nullptr);
    }
}

// Round 18
// 1984.078 us; speedup vs baseline: 1.0250x; 1.0250x over previous
//
#include <hip/hip_runtime.h>
#include <math.h>

// ---------- types / helpers ----------
typedef unsigned short u16;
typedef unsigned int   u32;
typedef u16   u16x8 __attribute__((ext_vector_type(8)));
typedef u16   u16x4 __attribute__((ext_vector_type(4)));
typedef short s16x8 __attribute__((ext_vector_type(8)));
typedef float f32x4 __attribute__((ext_vector_type(4)));

#define DEVFN static __device__ __forceinline__
#define GLOBAL_AS __attribute__((address_space(1)))
#define LDS_AS    __attribute__((address_space(3)))

constexpr int Bb = 16, Hh = 48, Ww = 48, Dd = 384;
constexpr int Nn = Hh * Ww;          // 2304 tokens per image
constexpr int NT = Bb * Nn;          // 36864 total tokens
constexpr int NH = 8, DHd = 48;      // heads, head dim
constexpr int INNER = NH * DHd;      // 384
constexpr int QC = 3 * INNER;        // 1152
constexpr int MF = 1536;
constexpr int DEPTH = 4;
constexpr int NCH = 6;               // n-split chunks for k_sim

DEVFN float bf2f(u16 u) { return __uint_as_float(((u32)u) << 16); }
DEVFN u16   f2bu(float f) { u32 x = __float_as_uint(f); return (u16)((x + 0x7FFFu + ((x >> 16) & 1u)) >> 16); }
DEVFN float geluf(float x) { return 0.5f * x * (1.0f + erff(x * 0.70710678118654752440f)); }

DEVFN void gload16(const u16* g, u16* lds_base) {
    __builtin_amdgcn_global_load_lds((const GLOBAL_AS void*)g, (LDS_AS void*)lds_base, 16, 0, 0);
}

// ---------- fp32 -> fp32 copy (seed residual stream in d_out) ----------
__global__ void k_copy(const float* __restrict__ in, float* __restrict__ X) {
    size_t i0 = ((size_t)blockIdx.x * 256 + threadIdx.x) * 4;
    *(f32x4*)(X + i0) = *(const f32x4*)(in + i0);
}

// ---------- transpose + fp32->bf16: in [K][N] f32 -> out [N][K] bf16 ----------
__global__ __launch_bounds__(256) void k_trb(const float* __restrict__ in, u16* __restrict__ out,
                                             int K, int N) {
    __shared__ float tile[64][65];
    in  += (size_t)blockIdx.z * K * N;
    out += (size_t)blockIdx.z * K * N;
    int k0 = blockIdx.y * 64, n0 = blockIdx.x * 64;
    int t = threadIdx.x;
    int r = t >> 4, c = (t & 15) * 4;
#pragma unroll
    for (int j = 0; j < 4; j++) {
        f32x4 v = *(const f32x4*)&in[(size_t)(k0 + r + j * 16) * N + n0 + c];
        tile[r + j * 16][c] = v[0]; tile[r + j * 16][c + 1] = v[1];
        tile[r + j * 16][c + 2] = v[2]; tile[r + j * 16][c + 3] = v[3];
    }
    __syncthreads();
#pragma unroll
    for (int j = 0; j < 4; j++) {
        u16x4 o;
#pragma unroll
        for (int i = 0; i < 4; i++) o[i] = f2bu(tile[c + i][r + j * 16]);
        *(u16x4*)&out[(size_t)(n0 + r + j * 16) * K + k0 + c] = o;
    }
}

// ---------- LayerNorm full: X fp32 [NT][384] -> bf16 out ----------
__global__ __launch_bounds__(256) void k_ln(const float* __restrict__ X,
                                            const float* __restrict__ g, const float* __restrict__ bta,
                                            u16* __restrict__ out) {
    int row = blockIdx.x * 4 + (threadIdx.x >> 6);
    int lane = threadIdx.x & 63;
    const float* xr = X + (size_t)row * Dd;
    float v[6]; float s = 0.f, s2 = 0.f;
#pragma unroll
    for (int j = 0; j < 6; j++) { v[j] = xr[lane + 64 * j]; s += v[j]; s2 += v[j] * v[j]; }
#pragma unroll
    for (int off = 32; off >= 1; off >>= 1) { s += __shfl_down(s, off); s2 += __shfl_down(s2, off); }
    s = __shfl(s, 0); s2 = __shfl(s2, 0);
    float m = s * (1.0f / Dd);
    float rstd = 1.0f / sqrtf(s2 * (1.0f / Dd) - m * m + 1e-5f);
    u16* orow = out + (size_t)row * Dd;
#pragma unroll
    for (int j = 0; j < 6; j++) {
        int c = lane + 64 * j;
        orow[c] = f2bu((v[j] - m) * rstd * g[c] + bta[c]);
    }
}

// ---------- MFMA GEMM: C[M,N] = A[M,K](bf16) @ BT[N,K](bf16), fp32 acc ----------
// ROUND-8 EXACT K-LOOP (best measured; no spill). MODE 0: store bf16.
// MODE 1: gelu(acc+bias)->bf16. MODE 2: X += scale*(acc+bias). MODE 3: MODE 0 +
// per-block column-ssq partials for q/k columns -> QP. MODE 4: MODE 2 + per-row
// LN partials (sum, sumsq of xnew over this block's 128 cols) -> QP as LNP,
// staged through the dead Ts LDS after a barrier.
// Round-17 lesson: staged/coalesced bf16 store cut WRITE_SIZE 2x but ADDED
// latency (kernel is latency-bound, not write-BW-bound) — keep scalar stores.
template <int MODE>
__global__ __launch_bounds__(512, 4) void k_mgemm(const u16* __restrict__ A, const u16* __restrict__ BT,
                                                  int Kdim, int Ndim,
                                                  const float* __restrict__ bias, const float* __restrict__ scale,
                                                  float* __restrict__ Xres, u16* __restrict__ Out,
                                                  float* __restrict__ QP) {
    __shared__ __align__(16) u16 Ts[3][24 * 512];
    __shared__ float QS[4][128];                 // MODE 3 cross-wave ssq partials
    const int gridX = Ndim >> 7;                 // N / 128
    const int nwg = gridX * (NT >> 8);           // * M/256
    const int cpx = nwg >> 3;
    const int id = blockIdx.x;
    const int id2 = (id & 7) * cpx + (id >> 3);  // bijective when nwg%8==0
    const int n0 = (id2 % gridX) * 128;
    const int m0 = (id2 / gridX) * 256;
    const int t = threadIdx.x;
    const int w = t >> 6, l = t & 63;
    const int wm = w >> 1, wn = w & 1;
    const int lr = l >> 2;                       // row-in-chunk
    const int sc = ((l & 3) ^ (lr & 3)) * 8;     // pre-swizzled source chunk (u16)
    const int fr = l & 15, rq = l >> 4;
    const int c0 = w * 3;                        // this wave's 3 staging chunks

    auto stage = [&](int buf, int k0) {
#pragma unroll
        for (int j = 0; j < 3; j++) {
            const int c = c0 + j;
            const u16* src = (c < 16)
                ? A  + (size_t)(m0 + c * 16 + lr) * Kdim + k0 + sc
                : BT + (size_t)(n0 + (c - 16) * 16 + lr) * Kdim + k0 + sc;
            gload16(src, Ts[buf] + c * 512);
        }
    };

    const int nt = Kdim >> 5;
    stage(0, 0);
    stage(1, 32);

    f32x4 acc[4][4] = {};
    for (int kt = 0; kt < nt; ++kt) {
        if (kt + 1 < nt) {
            asm volatile("s_waitcnt vmcnt(3)" ::: "memory");   // tile kt landed; kt+1 in flight
        } else {
            asm volatile("s_waitcnt vmcnt(0)" ::: "memory");
        }
        __builtin_amdgcn_s_barrier();
        __builtin_amdgcn_sched_barrier(0);
        if (kt + 2 < nt) stage((kt + 2) % 3, (kt + 2) * 32);
        const u16* ts = Ts[kt % 3];
        s16x8 af[4], bf[4];
#pragma unroll
        for (int f = 0; f < 4; f++) {
            const int row = wm * 64 + f * 16 + fr;
            af[f] = *(const s16x8*)&ts[row * 32 + ((rq ^ (fr & 3)) * 8)];
        }
#pragma unroll
        for (int g = 0; g < 4; g++) {
            const int row = wn * 64 + g * 16 + fr;
            bf[g] = *(const s16x8*)&ts[8192 + row * 32 + ((rq ^ (fr & 3)) * 8)];
        }
#pragma unroll
        for (int f = 0; f < 4; f++)
#pragma unroll
            for (int g = 0; g < 4; g++)
                acc[f][g] = __builtin_amdgcn_mfma_f32_16x16x32_bf16(af[f], bf[g], acc[f][g], 0, 0, 0);
    }

    float sq[4] = {0.f, 0.f, 0.f, 0.f};
    float rs[4][4], rs2[4][4];
    if (MODE == 4) {
#pragma unroll
        for (int f = 0; f < 4; f++)
#pragma unroll
            for (int r = 0; r < 4; r++) { rs[f][r] = 0.f; rs2[f][r] = 0.f; }
    }
#pragma unroll
    for (int g = 0; g < 4; g++) {
        const int n = n0 + wn * 64 + g * 16 + fr;
        float bv = (MODE == 1 || MODE == 2 || MODE == 4) ? bias[n] : 0.f;
        float sv = (MODE == 2 || MODE == 4) ? scale[n] : 0.f;
#pragma unroll
        for (int f = 0; f < 4; f++) {
            const size_t i0 = (size_t)(m0 + wm * 64 + f * 16 + rq * 4);
#pragma unroll
            for (int r = 0; r < 4; r++) {
                float v = acc[f][g][r];
                if (MODE == 0 || MODE == 3) {
                    Out[(i0 + r) * Ndim + n] = f2bu(v);
                    if (MODE == 3) sq[g] += v * v;
                } else if (MODE == 1) {
                    Out[(i0 + r) * Ndim + n] = f2bu(geluf(v + bv));
                } else {
                    float* xr = Xres + (i0 + r) * Ndim + n;
                    float xnew = *xr + sv * (v + bv);
                    *xr = xnew;
                    if (MODE == 4) { rs[f][r] += xnew; rs2[f][r] += xnew * xnew; }
                }
            }
        }
    }

    if (MODE == 3 && n0 < 768) {   // q,k columns only (block-uniform branch)
#pragma unroll
        for (int g = 0; g < 4; g++) {
            float s2 = sq[g];
            s2 += __shfl_down(s2, 32);
            s2 += __shfl_down(s2, 16);
            if (rq == 0) QS[wm][wn * 64 + g * 16 + fr] = s2;
        }
        __syncthreads();
        if (t < 128) {
            float s = QS[0][t] + QS[1][t] + QS[2][t] + QS[3][t];
            const int b_img = m0 / Nn, mset = (m0 % Nn) >> 8;
            QP[((size_t)(b_img * 9 + mset)) * 768 + n0 + t] = s;
        }
    }

    if (MODE == 4) {               // per-row LN partials via dead Ts LDS
        __syncthreads();           // all waves done reading Ts
        float* S = (float*)&Ts[0][0];       // 18432 floats available; use 16384
        const int col = wn * 16 + fr;
#pragma unroll
        for (int f = 0; f < 4; f++)
#pragma unroll
            for (int r = 0; r < 4; r++) {
                const int row = wm * 64 + f * 16 + rq * 4 + r;
                S[row * 32 + col] = rs[f][r];
                S[8192 + row * 32 + col] = rs2[f][r];
            }
        __syncthreads();
        const int row = t & 255;
        const int comp = t >> 8;   // 0: sum, 1: sumsq
        const float* Sb = S + comp * 8192 + row * 32;
        float s = 0.f;
#pragma unroll
        for (int i = 0; i < 32; i++) s += Sb[i];
        QP[(((size_t)(n0 >> 7)) * NT + (m0 + row)) * 2 + comp] = s;
    }
}

// ---------- finalize inv-norms: sum 9 m-set partials per (b, col<768) ----------
__global__ void k_nrm_fin(const float* __restrict__ QP, float* __restrict__ INVN) {
    int idx = blockIdx.x * 256 + threadIdx.x; // < 16*768
    int b = idx / 768, c = idx - b * 768;
    float s = 0;
#pragma unroll
    for (int ms = 0; ms < 9; ms++) s += QP[((size_t)(b * 9 + ms)) * 768 + c];
    INVN[idx] = 1.0f / fmaxf(sqrtf(s), 1e-12f);
}

// ---------- finalize LN stats from MODE-4 partials: LNS[row] = {m, rstd} ----------
__global__ void k_lnfin(const float* __restrict__ LNP, float* __restrict__ LNS) {
    int row = blockIdx.x * 256 + threadIdx.x;   // NT rows
    float s  = LNP[((size_t)0 * NT + row) * 2]     + LNP[((size_t)1 * NT + row) * 2]     + LNP[((size_t)2 * NT + row) * 2];
    float s2 = LNP[((size_t)0 * NT + row) * 2 + 1] + LNP[((size_t)1 * NT + row) * 2 + 1] + LNP[((size_t)2 * NT + row) * 2 + 1];
    float m = s * (1.0f / Dd);
    float rstd = 1.0f / sqrtf(s2 * (1.0f / Dd) - m * m + 1e-5f);
    LNS[row * 2] = m;
    LNS[row * 2 + 1] = rstd;
}

// ---------- sim partials via MFMA: SIMP[chunk][bh][d][e] over n-chunk ----------
__global__ __launch_bounds__(256) void k_sim(const u16* __restrict__ QKV, float* __restrict__ SIMP) {
    const int bh = blockIdx.x;
    const int b = bh >> 3, h = bh & 7;
    const int chunk = blockIdx.y;
    __shared__ float qt[48][65];
    __shared__ float kt[48][65];
    const int t = threadIdx.x;
    const int w = t >> 6, l = t & 63;
    const int fr = l & 15, rq = l >> 4;
    const int ti0 = w, ti1 = w + 4;              // tile 8 handled by wave 0 only
    f32x4 acc0 = {}, acc1 = {}, acc2 = {};

    auto doTile = [&](int ti, f32x4& a) {
        const int d0 = (ti / 3) * 16, e0 = (ti % 3) * 16;
#pragma unroll
        for (int s = 0; s < 2; s++) {
            const float* qp = &qt[d0 + fr][s * 32 + rq * 8];
            const float* kp = &kt[e0 + fr][s * 32 + rq * 8];
            s16x8 af, bf;
#pragma unroll
            for (int j = 0; j < 8; j++) {
                af[j] = (short)(__float_as_uint(qp[j]) >> 16);   // exact: values are bf16
                bf[j] = (short)(__float_as_uint(kp[j]) >> 16);
            }
            a = __builtin_amdgcn_mfma_f32_16x16x32_bf16(af, bf, a, 0, 0, 0);
        }
    };

    for (int c0 = chunk * (Nn / NCH); c0 < (chunk + 1) * (Nn / NCH); c0 += 64) {
        __syncthreads();
        for (int e = t; e < 48 * 64; e += 256) {
            int r = e / 48, d = e - r * 48;
            const u16* p = QKV + (size_t)(b * Nn + c0 + r) * QC + h * DHd + d;
            qt[d][r] = bf2f(p[0]);
            kt[d][r] = bf2f(p[INNER]);
        }
        __syncthreads();
        doTile(ti0, acc0);
        doTile(ti1, acc1);
        if (w == 0) doTile(8, acc2);
    }

    float* so = SIMP + ((size_t)chunk * (Bb * NH) + bh) * (DHd * DHd);
    auto wr = [&](int ti, const f32x4& a) {
        const int d0 = (ti / 3) * 16, e0 = (ti % 3) * 16;
#pragma unroll
        for (int r = 0; r < 4; r++) so[(d0 + rq * 4 + r) * DHd + e0 + fr] = a[r];
    };
    wr(ti0, acc0);
    wr(ti1, acc1);
    if (w == 0) wr(8, acc2);
}

// ---------- softmax: reduce SIMP chunks, scale, softmax over e -> SIM ----------
__global__ __launch_bounds__(256) void k_smax(const float* __restrict__ SIMP, float* __restrict__ SIM,
                                              const float* __restrict__ INVN, const float* __restrict__ temp) {
    int wid = blockIdx.x * 4 + (threadIdx.x >> 6);
    int lane = threadIdx.x & 63;
    int b = wid / (NH * DHd); int rem = wid - b * NH * DHd; int h = rem / DHd; int d = rem - h * DHd;
    int bh = b * NH + h;
    float et = expf(temp[h]);
    float invq = INVN[b * 768 + h * DHd + d];
    float myv = 0.f, mv = -3.0e38f;
    if (lane < DHd) {
        float s = 0.f;
#pragma unroll
        for (int c = 0; c < NCH; c++)
            s += SIMP[((size_t)c * (Bb * NH) + bh) * (DHd * DHd) + d * DHd + lane];
        myv = s * invq * INVN[b * 768 + 384 + h * DHd + lane] * et;
        mv = myv;
    }
#pragma unroll
    for (int off = 32; off >= 1; off >>= 1) mv = fmaxf(mv, __shfl_down(mv, off));
    mv = __shfl(mv, 0);
    float e = (lane < DHd) ? expf(myv - mv) : 0.f;
    float s = e;
#pragma unroll
    for (int off = 32; off >= 1; off >>= 1) s += __shfl_down(s, off);
    s = __shfl(s, 0);
    if (lane < DHd) SIM[(size_t)bh * (DHd * DHd) + d * DHd + lane] = e / s;
}

// ---------- out[b,n,h*48+d] = sum_e attn[d,e] * v[b,n,h,e]; one row per thread ----------
__global__ __launch_bounds__(256) void k_av(const u16* __restrict__ QKV, const float* __restrict__ SIM,
                                            u16* __restrict__ AOUT) {
    const int bh = blockIdx.x;
    const int b = bh >> 3, h = bh & 7;
    __shared__ __align__(16) float at[48][52];
    const int t = threadIdx.x;
    for (int e = t; e < 48 * 48; e += 256) at[e / 48][e % 48] = SIM[(size_t)bh * (DHd * DHd) + e];
    __syncthreads();
    const int r = blockIdx.y * 256 + t;   // grid.y = 9 -> 2304 rows
    const u16x8* vp = (const u16x8*)(QKV + (size_t)(b * Nn + r) * QC + 2 * INNER + h * DHd);
    f32x4 vv[12];
#pragma unroll
    for (int q8 = 0; q8 < 6; q8++) {
        u16x8 u = vp[q8];
#pragma unroll
        for (int j = 0; j < 8; j++) vv[q8 * 2 + (j >> 2)][j & 3] = bf2f(u[j]);
    }
    u16x8 ob[6];
#pragma unroll
    for (int d = 0; d < 48; d++) {
        f32x4 sv = {0.f, 0.f, 0.f, 0.f};
#pragma unroll
        for (int e4 = 0; e4 < 12; e4++) sv += *(const f32x4*)&at[d][e4 * 4] * vv[e4];
        ob[d >> 3][d & 7] = f2bu(sv[0] + sv[1] + sv[2] + sv[3]);
    }
    u16x8* orow = (u16x8*)(AOUT + (size_t)(b * Nn + r) * Dd + h * DHd);
#pragma unroll
    for (int q8 = 0; q8 < 6; q8++) orow[q8] = ob[q8];
}

// ---------- LPI fused kernel 1: LN-apply + dwconv3x3 + BN partial sums ----------
__global__ __launch_bounds__(384) void k_lpi1(const float* __restrict__ X, const float* __restrict__ LNS,
                                              const float* __restrict__ g, const float* __restrict__ bta,
                                              const float* __restrict__ wgt, const float* __restrict__ cbias,
                                              u16* __restrict__ CF, float* __restrict__ BNP) {
    const int c = threadIdx.x;
    const int by = blockIdx.x;
    const int y = by % Hh, b = by / Hh;
    const int x0 = blockIdx.y * (Ww / 2);
    float w9[9];
#pragma unroll
    for (int j = 0; j < 9; j++) w9[j] = wgt[c * 9 + j];
    const float gc = g[c], bc = bta[c], cb = cbias[c];
    const size_t base = (size_t)b * Nn * Dd;
    const float* lns = LNS + (size_t)b * Nn * 2;

    auto load3 = [&](int xx, float* col) {
        if (xx < 0 || xx >= Ww) { col[0] = col[1] = col[2] = 0.f; return; }
#pragma unroll
        for (int dy = 0; dy < 3; dy++) {
            int yy = y + dy - 1;
            if (yy < 0 || yy >= Hh) { col[dy] = 0.f; }
            else {
                int tok = yy * Ww + xx;
                float m = lns[tok * 2], r = lns[tok * 2 + 1];
                col[dy] = (X[base + (size_t)tok * Dd + c] - m) * r * gc + bc;
            }
        }
    };

    float A[3], B[3], C[3], T[3];
    load3(x0 - 1, A); load3(x0, B); load3(x0 + 1, C);
    float s = 0.f, s2 = 0.f;
    u16* crow = CF + base + ((size_t)y * Ww + x0) * Dd + c;
    for (int x = x0; x < x0 + Ww / 2; x++) {
        load3(x + 2, T);
        float acc = cb;
#pragma unroll
        for (int dy = 0; dy < 3; dy++)
            acc += w9[dy * 3] * A[dy] + w9[dy * 3 + 1] * B[dy] + w9[dy * 3 + 2] * C[dy];
        crow[(size_t)(x - x0) * Dd] = f2bu(acc);
        s += acc; s2 += acc * acc;
#pragma unroll
        for (int dy = 0; dy < 3; dy++) { A[dy] = B[dy]; B[dy] = C[dy]; C[dy] = T[dy]; }
    }
    float* o = BNP + ((size_t)by * 2 + blockIdx.y) * 768;
    o[c] = s; o[384 + c] = s2;
}

// ---------- BN reduce: 1536 partial blocks -> 64 -> fused affine (bnA, bnB) ----------
__global__ __launch_bounds__(384) void k_bnred1(const float* __restrict__ BNP, float* __restrict__ BNQ) {
    int t = threadIdx.x, blk = blockIdx.x;  // 64 blocks, 24 partials each
    float s = 0.f, s2 = 0.f;
    for (int i = blk * 24; i < blk * 24 + 24; i++) { s += BNP[(size_t)i * 768 + t]; s2 += BNP[(size_t)i * 768 + 384 + t]; }
    BNQ[(size_t)blk * 768 + t] = s; BNQ[(size_t)blk * 768 + 384 + t] = s2;
}

__global__ __launch_bounds__(384) void k_bnred2(const float* __restrict__ BNQ,
                                                const float* __restrict__ bng, const float* __restrict__ bnb,
                                                float* __restrict__ BNC) {
    int t = threadIdx.x;
    float s = 0.f, s2 = 0.f;
    for (int i = 0; i < 64; i++) { s += BNQ[(size_t)i * 768 + t]; s2 += BNQ[(size_t)i * 768 + 384 + t]; }
    float m = s / NT;
    float var = s2 / NT - m * m;
    float r = 1.0f / sqrtf(var + 1e-5f);
    BNC[t] = r * bng[t];
    BNC[384 + t] = bnb[t] - m * r * bng[t];
}

// ---------- LPI fused kernel 2: BN+GELU + dwconv3x3 + residual into X ----------
__global__ __launch_bounds__(384) void k_lpi2(const u16* __restrict__ CF, const float* __restrict__ BNC,
                                              const float* __restrict__ wgt, const float* __restrict__ cbias,
                                              const float* __restrict__ scale, float* __restrict__ X) {
    const int c = threadIdx.x;
    const int by = blockIdx.x;
    const int y = by % Hh, b = by / Hh;
    const int x0 = blockIdx.y * (Ww / 2);
    float w9[9];
#pragma unroll
    for (int j = 0; j < 9; j++) w9[j] = wgt[c * 9 + j];
    const float bnA = BNC[c], bnB = BNC[384 + c];
    const float cb = cbias[c], sc = scale[c];
    const size_t base = (size_t)b * Nn * Dd;

    auto load3 = [&](int xx, float* col) {
        if (xx < 0 || xx >= Ww) { col[0] = col[1] = col[2] = 0.f; return; }
#pragma unroll
        for (int dy = 0; dy < 3; dy++) {
            int yy = y + dy - 1;
            if (yy < 0 || yy >= Hh) { col[dy] = 0.f; }
            else {
                int tok = yy * Ww + xx;
                col[dy] = geluf(bf2f(CF[base + (size_t)tok * Dd + c]) * bnA + bnB);
            }
        }
    };

    float A[3], B[3], C[3], T[3];
    load3(x0 - 1, A); load3(x0, B); load3(x0 + 1, C);
    float* xrow = X + base + ((size_t)y * Ww + x0) * Dd + c;
    for (int x = x0; x < x0 + Ww / 2; x++) {
        load3(x + 2, T);
        float acc = cb;
#pragma unroll
        for (int dy = 0; dy < 3; dy++)
            acc += w9[dy * 3] * A[dy] + w9[dy * 3 + 1] * B[dy] + w9[dy * 3 + 2] * C[dy];
        xrow[(size_t)(x - x0) * Dd] += sc * acc;
#pragma unroll
        for (int dy = 0; dy < 3; dy++) { A[dy] = B[dy]; B[dy] = C[dy]; C[dy] = T[dy]; }
    }
}

// ---------- host launch ----------
extern "C" void kernel_launch(void* const* d_in, const int* in_sizes, int n_in,
                              void* d_out, int out_size, void* d_ws, size_t ws_size,
                              hipStream_t stream) {
    const float* x     = (const float*)d_in[0];
    const float* ln1_g = (const float*)d_in[1];
    const float* ln1_b = (const float*)d_in[2];
    const float* w_qkv = (const float*)d_in[3];
    const float* temp  = (const float*)d_in[4];
    const float* w_out = (const float*)d_in[5];
    const float* b_out = (const float*)d_in[6];
    const float* s_att = (const float*)d_in[7];
    const float* lpi_g = (const float*)d_in[8];
    const float* lpi_b = (const float*)d_in[9];
    const float* c1w   = (const float*)d_in[10];
    const float* c1b   = (const float*)d_in[11];
    const float* bng   = (const float*)d_in[12];
    const float* bnb   = (const float*)d_in[13];
    const float* c2w   = (const float*)d_in[14];
    const float* c2b   = (const float*)d_in[15];
    const float* s_lpi = (const float*)d_in[16];
    const float* ff_g  = (const float*)d_in[17];
    const float* ff_b  = (const float*)d_in[18];
    const float* w1    = (const float*)d_in[19];
    const float* b1    = (const float*)d_in[20];
    const float* w2    = (const float*)d_in[21];
    const float* b2    = (const float*)d_in[22];
    const float* s_ff  = (const float*)d_in[23];

    float* X = (float*)d_out;  // residual stream lives in d_out (fp32)

    char* p = (char*)d_ws;
    auto carve = [&](size_t bytes) -> char* { char* r = p; p += (bytes + 255) / 256 * 256; return r; };
    u16*   BIG  = (u16*)  carve((size_t)NT * MF * 2);            // QKV / CF / FF1
    u16*   Hb   = (u16*)  carve((size_t)NT * Dd * 2);            // LN outputs
    float* SIM  = (float*)carve((size_t)Bb * NH * DHd * DHd * 4);
    float* SIMP = (float*)carve((size_t)NCH * Bb * NH * DHd * DHd * 4);
    float* INVN = (float*)carve((size_t)Bb * 768 * 4);
    float* QP   = (float*)carve((size_t)Bb * 9 * 768 * 4);
    float* LNP  = (float*)carve((size_t)3 * NT * 2 * 4);
    float* LNS  = (float*)carve((size_t)NT * 2 * 4);
    float* BNP  = (float*)carve((size_t)1536 * 768 * 4);
    float* BNQ  = (float*)carve((size_t)64 * 768 * 4);
    float* BNC  = (float*)carve((size_t)768 * 4);
    u16*   WQT  = (u16*)  carve((size_t)DEPTH * Dd * QC * 2);    // bf16 transposed weights [N][K]
    u16*   WOT  = (u16*)  carve((size_t)DEPTH * INNER * Dd * 2);
    u16*   W1T  = (u16*)  carve((size_t)DEPTH * Dd * MF * 2);
    u16*   W2T  = (u16*)  carve((size_t)DEPTH * MF * Dd * 2);
    u16*   AO   = BIG + (size_t)NT * QC;   // attention out aliases tail of BIG
    u16*   CF   = BIG;                     // conv1 bf16 out aliases BIG (QKV dead by then)

    k_trb<<<dim3(QC / 64, Dd / 64, DEPTH), 256, 0, stream>>>(w_qkv, WQT, Dd, QC);
    k_trb<<<dim3(Dd / 64, INNER / 64, DEPTH), 256, 0, stream>>>(w_out, WOT, INNER, Dd);
    k_trb<<<dim3(MF / 64, Dd / 64, DEPTH), 256, 0, stream>>>(w1, W1T, Dd, MF);
    k_trb<<<dim3(Dd / 64, MF / 64, DEPTH), 256, 0, stream>>>(w2, W2T, MF, Dd);

    k_copy<<<NT * Dd / 1024, 256, 0, stream>>>(x, X);
    for (int L = 0; L < DEPTH; L++) {
        // ---- XCA ----
        k_ln<<<NT / 4, 256, 0, stream>>>(X, ln1_g + L * Dd, ln1_b + L * Dd, Hb);
        k_mgemm<3><<<(QC / 128) * (NT / 256), 512, 0, stream>>>(Hb, WQT + (size_t)L * Dd * QC, Dd, QC,
                                                                nullptr, nullptr, nullptr, BIG, QP);
        k_nrm_fin<<<Bb * 768 / 256, 256, 0, stream>>>(QP, INVN);
        k_sim<<<dim3(Bb * NH, NCH), 256, 0, stream>>>(BIG, SIMP);
        k_smax<<<Bb * NH * DHd / 4, 256, 0, stream>>>(SIMP, SIM, INVN, temp + L * NH);
        k_av<<<dim3(Bb * NH, Nn / 256), 256, 0, stream>>>(BIG, SIM, AO);
        // attn-out GEMM also emits per-row LN partials (MODE 4) -> LNP
        k_mgemm<4><<<(Dd / 128) * (NT / 256), 512, 0, stream>>>(AO, WOT + (size_t)L * INNER * Dd, INNER, Dd,
                                                                b_out + L * Dd, s_att + L * Dd, X, nullptr, LNP);
        k_lnfin<<<NT / 256, 256, 0, stream>>>(LNP, LNS);
        // ---- LPI (fused) ----
        k_lpi1<<<dim3(Bb * Hh, 2), 384, 0, stream>>>(X, LNS, lpi_g + L * Dd, lpi_b + L * Dd,
                                                     c1w + (size_t)L * Dd * 9, c1b + L * Dd, CF, BNP);
        k_bnred1<<<64, 384, 0, stream>>>(BNP, BNQ);
        k_bnred2<<<1, 384, 0, stream>>>(BNQ, bng + L * Dd, bnb + L * Dd, BNC);
        k_lpi2<<<dim3(Bb * Hh, 2), 384, 0, stream>>>(CF, BNC, c2w + (size_t)L * Dd * 9, c2b + L * Dd,
                                                     s_lpi + L * Dd, X);
        // ---- FF ----
        k_ln<<<NT / 4, 256, 0, stream>>>(X, ff_g + L * Dd, ff_b + L * Dd, Hb);
        k_mgemm<1><<<(MF / 128) * (NT / 256), 512, 0, stream>>>(Hb, W1T + (size_t)L * Dd * MF, Dd, MF,
                                                                b1 + L * MF, nullptr, nullptr, BIG, nullptr);
        k_mgemm<2><<<(Dd / 128) * (NT / 256), 512, 0, stream>>>(BIG, W2T + (size_t)L * MF * Dd, MF, Dd,
                                                                b2 + L * Dd, s_ff + L * Dd, X, nullptr, nullptr);
    }
}

// Round 19
// 1928.910 us; speedup vs baseline: 1.0544x; 1.0286x over previous
//
#include <hip/hip_runtime.h>
#include <math.h>

// ---------- types / helpers ----------
typedef unsigned short u16;
typedef unsigned int   u32;
typedef u16   u16x8 __attribute__((ext_vector_type(8)));
typedef u16   u16x4 __attribute__((ext_vector_type(4)));
typedef short s16x8 __attribute__((ext_vector_type(8)));
typedef float f32x4 __attribute__((ext_vector_type(4)));

#define DEVFN static __device__ __forceinline__
#define GLOBAL_AS __attribute__((address_space(1)))
#define LDS_AS    __attribute__((address_space(3)))

constexpr int Bb = 16, Hh = 48, Ww = 48, Dd = 384;
constexpr int Nn = Hh * Ww;          // 2304 tokens per image
constexpr int NT = Bb * Nn;          // 36864 total tokens
constexpr int NH = 8, DHd = 48;      // heads, head dim
constexpr int INNER = NH * DHd;      // 384
constexpr int QC = 3 * INNER;        // 1152
constexpr int MF = 1536;
constexpr int DEPTH = 4;
constexpr int NCH = 6;               // n-split chunks for k_sim

DEVFN float bf2f(u16 u) { return __uint_as_float(((u32)u) << 16); }
DEVFN u16   f2bu(float f) { u32 x = __float_as_uint(f); return (u16)((x + 0x7FFFu + ((x >> 16) & 1u)) >> 16); }
DEVFN float geluf(float x) { return 0.5f * x * (1.0f + erff(x * 0.70710678118654752440f)); }

DEVFN void gload16(const u16* g, u16* lds_base) {
    __builtin_amdgcn_global_load_lds((const GLOBAL_AS void*)g, (LDS_AS void*)lds_base, 16, 0, 0);
}

// ---------- fp32 -> fp32 copy (seed residual stream in d_out) ----------
__global__ void k_copy(const float* __restrict__ in, float* __restrict__ X) {
    size_t i0 = ((size_t)blockIdx.x * 256 + threadIdx.x) * 4;
    *(f32x4*)(X + i0) = *(const f32x4*)(in + i0);
}

// ---------- transpose + fp32->bf16: in [K][N] f32 -> out [N][K] bf16 ----------
__global__ __launch_bounds__(256) void k_trb(const float* __restrict__ in, u16* __restrict__ out,
                                             int K, int N) {
    __shared__ float tile[64][65];
    in  += (size_t)blockIdx.z * K * N;
    out += (size_t)blockIdx.z * K * N;
    int k0 = blockIdx.y * 64, n0 = blockIdx.x * 64;
    int t = threadIdx.x;
    int r = t >> 4, c = (t & 15) * 4;
#pragma unroll
    for (int j = 0; j < 4; j++) {
        f32x4 v = *(const f32x4*)&in[(size_t)(k0 + r + j * 16) * N + n0 + c];
        tile[r + j * 16][c] = v[0]; tile[r + j * 16][c + 1] = v[1];
        tile[r + j * 16][c + 2] = v[2]; tile[r + j * 16][c + 3] = v[3];
    }
    __syncthreads();
#pragma unroll
    for (int j = 0; j < 4; j++) {
        u16x4 o;
#pragma unroll
        for (int i = 0; i < 4; i++) o[i] = f2bu(tile[c + i][r + j * 16]);
        *(u16x4*)&out[(size_t)(n0 + r + j * 16) * K + k0 + c] = o;
    }
}

// ---------- LayerNorm full: X fp32 [NT][384] -> bf16 out ----------
__global__ __launch_bounds__(256) void k_ln(const float* __restrict__ X,
                                            const float* __restrict__ g, const float* __restrict__ bta,
                                            u16* __restrict__ out) {
    int row = blockIdx.x * 4 + (threadIdx.x >> 6);
    int lane = threadIdx.x & 63;
    const float* xr = X + (size_t)row * Dd;
    float v[6]; float s = 0.f, s2 = 0.f;
#pragma unroll
    for (int j = 0; j < 6; j++) { v[j] = xr[lane + 64 * j]; s += v[j]; s2 += v[j] * v[j]; }
#pragma unroll
    for (int off = 32; off >= 1; off >>= 1) { s += __shfl_down(s, off); s2 += __shfl_down(s2, off); }
    s = __shfl(s, 0); s2 = __shfl(s2, 0);
    float m = s * (1.0f / Dd);
    float rstd = 1.0f / sqrtf(s2 * (1.0f / Dd) - m * m + 1e-5f);
    u16* orow = out + (size_t)row * Dd;
#pragma unroll
    for (int j = 0; j < 6; j++) {
        int c = lane + 64 * j;
        orow[c] = f2bu((v[j] - m) * rstd * g[c] + bta[c]);
    }
}

// ---------- MFMA GEMM: C[M,N] = A[M,K](bf16) @ BT[N,K](bf16), fp32 acc ----------
// ROUND-8 EXACT K-LOOP (best measured; no spill). MODE 0: store bf16.
// MODE 1: gelu(acc+bias)->bf16. MODE 2: X += scale*(acc+bias). MODE 3: MODE 0 +
// per-block column-ssq partials for q/k columns -> QP. MODE 4: MODE 2 + per-row
// LN partials (sum, sumsq of xnew over this block's 128 cols) -> QP as LNP,
// staged through the dead Ts LDS after a barrier.
template <int MODE>
__global__ __launch_bounds__(512, 4) void k_mgemm(const u16* __restrict__ A, const u16* __restrict__ BT,
                                                  int Kdim, int Ndim,
                                                  const float* __restrict__ bias, const float* __restrict__ scale,
                                                  float* __restrict__ Xres, u16* __restrict__ Out,
                                                  float* __restrict__ QP) {
    __shared__ __align__(16) u16 Ts[3][24 * 512];
    __shared__ float QS[4][128];                 // MODE 3 cross-wave ssq partials
    const int gridX = Ndim >> 7;                 // N / 128
    const int nwg = gridX * (NT >> 8);           // * M/256
    const int cpx = nwg >> 3;
    const int id = blockIdx.x;
    const int id2 = (id & 7) * cpx + (id >> 3);  // bijective when nwg%8==0
    const int n0 = (id2 % gridX) * 128;
    const int m0 = (id2 / gridX) * 256;
    const int t = threadIdx.x;
    const int w = t >> 6, l = t & 63;
    const int wm = w >> 1, wn = w & 1;
    const int lr = l >> 2;                       // row-in-chunk
    const int sc = ((l & 3) ^ (lr & 3)) * 8;     // pre-swizzled source chunk (u16)
    const int fr = l & 15, rq = l >> 4;
    const int c0 = w * 3;                        // this wave's 3 staging chunks

    auto stage = [&](int buf, int k0) {
#pragma unroll
        for (int j = 0; j < 3; j++) {
            const int c = c0 + j;
            const u16* src = (c < 16)
                ? A  + (size_t)(m0 + c * 16 + lr) * Kdim + k0 + sc
                : BT + (size_t)(n0 + (c - 16) * 16 + lr) * Kdim + k0 + sc;
            gload16(src, Ts[buf] + c * 512);
        }
    };

    const int nt = Kdim >> 5;
    stage(0, 0);
    stage(1, 32);

    f32x4 acc[4][4] = {};
    for (int kt = 0; kt < nt; ++kt) {
        if (kt + 1 < nt) {
            asm volatile("s_waitcnt vmcnt(3)" ::: "memory");   // tile kt landed; kt+1 in flight
        } else {
            asm volatile("s_waitcnt vmcnt(0)" ::: "memory");
        }
        __builtin_amdgcn_s_barrier();
        __builtin_amdgcn_sched_barrier(0);
        if (kt + 2 < nt) stage((kt + 2) % 3, (kt + 2) * 32);
        const u16* ts = Ts[kt % 3];
        s16x8 af[4], bf[4];
#pragma unroll
        for (int f = 0; f < 4; f++) {
            const int row = wm * 64 + f * 16 + fr;
            af[f] = *(const s16x8*)&ts[row * 32 + ((rq ^ (fr & 3)) * 8)];
        }
#pragma unroll
        for (int g = 0; g < 4; g++) {
            const int row = wn * 64 + g * 16 + fr;
            bf[g] = *(const s16x8*)&ts[8192 + row * 32 + ((rq ^ (fr & 3)) * 8)];
        }
#pragma unroll
        for (int f = 0; f < 4; f++)
#pragma unroll
            for (int g = 0; g < 4; g++)
                acc[f][g] = __builtin_amdgcn_mfma_f32_16x16x32_bf16(af[f], bf[g], acc[f][g], 0, 0, 0);
    }

    float sq[4] = {0.f, 0.f, 0.f, 0.f};
    float rs[4][4], rs2[4][4];
    if (MODE == 4) {
#pragma unroll
        for (int f = 0; f < 4; f++)
#pragma unroll
            for (int r = 0; r < 4; r++) { rs[f][r] = 0.f; rs2[f][r] = 0.f; }
    }
#pragma unroll
    for (int g = 0; g < 4; g++) {
        const int n = n0 + wn * 64 + g * 16 + fr;
        float bv = (MODE == 1 || MODE == 2 || MODE == 4) ? bias[n] : 0.f;
        float sv = (MODE == 2 || MODE == 4) ? scale[n] : 0.f;
#pragma unroll
        for (int f = 0; f < 4; f++) {
            const size_t i0 = (size_t)(m0 + wm * 64 + f * 16 + rq * 4);
#pragma unroll
            for (int r = 0; r < 4; r++) {
                float v = acc[f][g][r];
                if (MODE == 0 || MODE == 3) {
                    Out[(i0 + r) * Ndim + n] = f2bu(v);
                    if (MODE == 3) sq[g] += v * v;
                } else if (MODE == 1) {
                    Out[(i0 + r) * Ndim + n] = f2bu(geluf(v + bv));
                } else {
                    float* xr = Xres + (i0 + r) * Ndim + n;
                    float xnew = *xr + sv * (v + bv);
                    *xr = xnew;
                    if (MODE == 4) { rs[f][r] += xnew; rs2[f][r] += xnew * xnew; }
                }
            }
        }
    }

    if (MODE == 3 && n0 < 768) {   // q,k columns only (block-uniform branch)
#pragma unroll
        for (int g = 0; g < 4; g++) {
            float s2 = sq[g];
            s2 += __shfl_down(s2, 32);
            s2 += __shfl_down(s2, 16);
            if (rq == 0) QS[wm][wn * 64 + g * 16 + fr] = s2;
        }
        __syncthreads();
        if (t < 128) {
            float s = QS[0][t] + QS[1][t] + QS[2][t] + QS[3][t];
            const int b_img = m0 / Nn, mset = (m0 % Nn) >> 8;
            QP[((size_t)(b_img * 9 + mset)) * 768 + n0 + t] = s;
        }
    }

    if (MODE == 4) {               // per-row LN partials via dead Ts LDS
        __syncthreads();           // all waves done reading Ts
        float* S = (float*)&Ts[0][0];       // 18432 floats available; use 16384
        const int col = wn * 16 + fr;
#pragma unroll
        for (int f = 0; f < 4; f++)
#pragma unroll
            for (int r = 0; r < 4; r++) {
                const int row = wm * 64 + f * 16 + rq * 4 + r;
                S[row * 32 + col] = rs[f][r];
                S[8192 + row * 32 + col] = rs2[f][r];
            }
        __syncthreads();
        const int row = t & 255;
        const int comp = t >> 8;   // 0: sum, 1: sumsq
        const float* Sb = S + comp * 8192 + row * 32;
        float s = 0.f;
#pragma unroll
        for (int i = 0; i < 32; i++) s += Sb[i];
        QP[(((size_t)(n0 >> 7)) * NT + (m0 + row)) * 2 + comp] = s;
    }
}

// ---------- finalize inv-norms: sum 9 m-set partials per (b, col<768) ----------
__global__ void k_nrm_fin(const float* __restrict__ QP, float* __restrict__ INVN) {
    int idx = blockIdx.x * 256 + threadIdx.x; // < 16*768
    int b = idx / 768, c = idx - b * 768;
    float s = 0;
#pragma unroll
    for (int ms = 0; ms < 9; ms++) s += QP[((size_t)(b * 9 + ms)) * 768 + c];
    INVN[idx] = 1.0f / fmaxf(sqrtf(s), 1e-12f);
}

// ---------- finalize LN stats from MODE-4 partials: LNS[row] = {m, rstd} ----------
__global__ void k_lnfin(const float* __restrict__ LNP, float* __restrict__ LNS) {
    int row = blockIdx.x * 256 + threadIdx.x;   // NT rows
    float s  = LNP[((size_t)0 * NT + row) * 2]     + LNP[((size_t)1 * NT + row) * 2]     + LNP[((size_t)2 * NT + row) * 2];
    float s2 = LNP[((size_t)0 * NT + row) * 2 + 1] + LNP[((size_t)1 * NT + row) * 2 + 1] + LNP[((size_t)2 * NT + row) * 2 + 1];
    float m = s * (1.0f / Dd);
    float rstd = 1.0f / sqrtf(s2 * (1.0f / Dd) - m * m + 1e-5f);
    LNS[row * 2] = m;
    LNS[row * 2 + 1] = rstd;
}

// ---------- sim partials via MFMA: SIMP[chunk][bh][d][e] over n-chunk ----------
__global__ __launch_bounds__(256) void k_sim(const u16* __restrict__ QKV, float* __restrict__ SIMP) {
    const int bh = blockIdx.x;
    const int b = bh >> 3, h = bh & 7;
    const int chunk = blockIdx.y;
    __shared__ float qt[48][65];
    __shared__ float kt[48][65];
    const int t = threadIdx.x;
    const int w = t >> 6, l = t & 63;
    const int fr = l & 15, rq = l >> 4;
    const int ti0 = w, ti1 = w + 4;              // tile 8 handled by wave 0 only
    f32x4 acc0 = {}, acc1 = {}, acc2 = {};

    auto doTile = [&](int ti, f32x4& a) {
        const int d0 = (ti / 3) * 16, e0 = (ti % 3) * 16;
#pragma unroll
        for (int s = 0; s < 2; s++) {
            const float* qp = &qt[d0 + fr][s * 32 + rq * 8];
            const float* kp = &kt[e0 + fr][s * 32 + rq * 8];
            s16x8 af, bf;
#pragma unroll
            for (int j = 0; j < 8; j++) {
                af[j] = (short)(__float_as_uint(qp[j]) >> 16);   // exact: values are bf16
                bf[j] = (short)(__float_as_uint(kp[j]) >> 16);
            }
            a = __builtin_amdgcn_mfma_f32_16x16x32_bf16(af, bf, a, 0, 0, 0);
        }
    };

    for (int c0 = chunk * (Nn / NCH); c0 < (chunk + 1) * (Nn / NCH); c0 += 64) {
        __syncthreads();
        for (int e = t; e < 48 * 64; e += 256) {
            int r = e / 48, d = e - r * 48;
            const u16* p = QKV + (size_t)(b * Nn + c0 + r) * QC + h * DHd + d;
            qt[d][r] = bf2f(p[0]);
            kt[d][r] = bf2f(p[INNER]);
        }
        __syncthreads();
        doTile(ti0, acc0);
        doTile(ti1, acc1);
        if (w == 0) doTile(8, acc2);
    }

    float* so = SIMP + ((size_t)chunk * (Bb * NH) + bh) * (DHd * DHd);
    auto wr = [&](int ti, const f32x4& a) {
        const int d0 = (ti / 3) * 16, e0 = (ti % 3) * 16;
#pragma unroll
        for (int r = 0; r < 4; r++) so[(d0 + rq * 4 + r) * DHd + e0 + fr] = a[r];
    };
    wr(ti0, acc0);
    wr(ti1, acc1);
    if (w == 0) wr(8, acc2);
}

// ---------- softmax: reduce SIMP chunks, scale, softmax over e -> SIM ----------
__global__ __launch_bounds__(256) void k_smax(const float* __restrict__ SIMP, float* __restrict__ SIM,
                                              const float* __restrict__ INVN, const float* __restrict__ temp) {
    int wid = blockIdx.x * 4 + (threadIdx.x >> 6);
    int lane = threadIdx.x & 63;
    int b = wid / (NH * DHd); int rem = wid - b * NH * DHd; int h = rem / DHd; int d = rem - h * DHd;
    int bh = b * NH + h;
    float et = expf(temp[h]);
    float invq = INVN[b * 768 + h * DHd + d];
    float myv = 0.f, mv = -3.0e38f;
    if (lane < DHd) {
        float s = 0.f;
#pragma unroll
        for (int c = 0; c < NCH; c++)
            s += SIMP[((size_t)c * (Bb * NH) + bh) * (DHd * DHd) + d * DHd + lane];
        myv = s * invq * INVN[b * 768 + 384 + h * DHd + lane] * et;
        mv = myv;
    }
#pragma unroll
    for (int off = 32; off >= 1; off >>= 1) mv = fmaxf(mv, __shfl_down(mv, off));
    mv = __shfl(mv, 0);
    float e = (lane < DHd) ? expf(myv - mv) : 0.f;
    float s = e;
#pragma unroll
    for (int off = 32; off >= 1; off >>= 1) s += __shfl_down(s, off);
    s = __shfl(s, 0);
    if (lane < DHd) SIM[(size_t)bh * (DHd * DHd) + d * DHd + lane] = e / s;
}

// ---------- out[b,n,h*48+d] = sum_e attn[d,e] * v[b,n,h,e]; one row per thread ----------
__global__ __launch_bounds__(256) void k_av(const u16* __restrict__ QKV, const float* __restrict__ SIM,
                                            u16* __restrict__ AOUT) {
    const int bh = blockIdx.x;
    const int b = bh >> 3, h = bh & 7;
    __shared__ __align__(16) float at[48][52];
    const int t = threadIdx.x;
    for (int e = t; e < 48 * 48; e += 256) at[e / 48][e % 48] = SIM[(size_t)bh * (DHd * DHd) + e];
    __syncthreads();
    const int r = blockIdx.y * 256 + t;   // grid.y = 9 -> 2304 rows
    const u16x8* vp = (const u16x8*)(QKV + (size_t)(b * Nn + r) * QC + 2 * INNER + h * DHd);
    f32x4 vv[12];
#pragma unroll
    for (int q8 = 0; q8 < 6; q8++) {
        u16x8 u = vp[q8];
#pragma unroll
        for (int j = 0; j < 8; j++) vv[q8 * 2 + (j >> 2)][j & 3] = bf2f(u[j]);
    }
    u16x8 ob[6];
#pragma unroll
    for (int d = 0; d < 48; d++) {
        f32x4 sv = {0.f, 0.f, 0.f, 0.f};
#pragma unroll
        for (int e4 = 0; e4 < 12; e4++) sv += *(const f32x4*)&at[d][e4 * 4] * vv[e4];
        ob[d >> 3][d & 7] = f2bu(sv[0] + sv[1] + sv[2] + sv[3]);
    }
    u16x8* orow = (u16x8*)(AOUT + (size_t)(b * Nn + r) * Dd + h * DHd);
#pragma unroll
    for (int q8 = 0; q8 < 6; q8++) orow[q8] = ob[q8];
}

// ---------- LPI fused kernel 1: LN-apply + dwconv3x3 + BN partial sums ----------
// XCD-swizzled block mapping: each XCD owns 96 consecutive (b,y) rows so the
// 3x y-halo re-reads hit the same L2 instead of re-fetching from HBM.
__global__ __launch_bounds__(384) void k_lpi1(const float* __restrict__ X, const float* __restrict__ LNS,
                                              const float* __restrict__ g, const float* __restrict__ bta,
                                              const float* __restrict__ wgt, const float* __restrict__ cbias,
                                              u16* __restrict__ CF, float* __restrict__ BNP) {
    const int c = threadIdx.x;
    const int id = blockIdx.x;
    const int by = (id & 7) * (Bb * Hh / 8) + (id >> 3);   // bijective: 768 % 8 == 0
    const int y = by % Hh, b = by / Hh;
    const int x0 = blockIdx.y * (Ww / 2);
    float w9[9];
#pragma unroll
    for (int j = 0; j < 9; j++) w9[j] = wgt[c * 9 + j];
    const float gc = g[c], bc = bta[c], cb = cbias[c];
    const size_t base = (size_t)b * Nn * Dd;
    const float* lns = LNS + (size_t)b * Nn * 2;

    auto load3 = [&](int xx, float* col) {
        if (xx < 0 || xx >= Ww) { col[0] = col[1] = col[2] = 0.f; return; }
#pragma unroll
        for (int dy = 0; dy < 3; dy++) {
            int yy = y + dy - 1;
            if (yy < 0 || yy >= Hh) { col[dy] = 0.f; }
            else {
                int tok = yy * Ww + xx;
                float m = lns[tok * 2], r = lns[tok * 2 + 1];
                col[dy] = (X[base + (size_t)tok * Dd + c] - m) * r * gc + bc;
            }
        }
    };

    float A[3], B[3], C[3], T[3];
    load3(x0 - 1, A); load3(x0, B); load3(x0 + 1, C);
    float s = 0.f, s2 = 0.f;
    u16* crow = CF + base + ((size_t)y * Ww + x0) * Dd + c;
    for (int x = x0; x < x0 + Ww / 2; x++) {
        load3(x + 2, T);
        float acc = cb;
#pragma unroll
        for (int dy = 0; dy < 3; dy++)
            acc += w9[dy * 3] * A[dy] + w9[dy * 3 + 1] * B[dy] + w9[dy * 3 + 2] * C[dy];
        crow[(size_t)(x - x0) * Dd] = f2bu(acc);
        s += acc; s2 += acc * acc;
#pragma unroll
        for (int dy = 0; dy < 3; dy++) { A[dy] = B[dy]; B[dy] = C[dy]; C[dy] = T[dy]; }
    }
    float* o = BNP + ((size_t)by * 2 + blockIdx.y) * 768;
    o[c] = s; o[384 + c] = s2;
}

// ---------- BN reduce: 1536 partial blocks -> 64 -> fused affine (bnA, bnB) ----------
__global__ __launch_bounds__(384) void k_bnred1(const float* __restrict__ BNP, float* __restrict__ BNQ) {
    int t = threadIdx.x, blk = blockIdx.x;  // 64 blocks, 24 partials each
    float s = 0.f, s2 = 0.f;
    for (int i = blk * 24; i < blk * 24 + 24; i++) { s += BNP[(size_t)i * 768 + t]; s2 += BNP[(size_t)i * 768 + 384 + t]; }
    BNQ[(size_t)blk * 768 + t] = s; BNQ[(size_t)blk * 768 + 384 + t] = s2;
}

__global__ __launch_bounds__(384) void k_bnred2(const float* __restrict__ BNQ,
                                                const float* __restrict__ bng, const float* __restrict__ bnb,
                                                float* __restrict__ BNC) {
    int t = threadIdx.x;
    float s = 0.f, s2 = 0.f;
    for (int i = 0; i < 64; i++) { s += BNQ[(size_t)i * 768 + t]; s2 += BNQ[(size_t)i * 768 + 384 + t]; }
    float m = s / NT;
    float var = s2 / NT - m * m;
    float r = 1.0f / sqrtf(var + 1e-5f);
    BNC[t] = r * bng[t];
    BNC[384 + t] = bnb[t] - m * r * bng[t];
}

// ---------- LPI fused kernel 2: BN+GELU + dwconv3x3 + residual into X ----------
// Same XCD-swizzled (b,y) mapping as k_lpi1 for halo L2 locality.
__global__ __launch_bounds__(384) void k_lpi2(const u16* __restrict__ CF, const float* __restrict__ BNC,
                                              const float* __restrict__ wgt, const float* __restrict__ cbias,
                                              const float* __restrict__ scale, float* __restrict__ X) {
    const int c = threadIdx.x;
    const int id = blockIdx.x;
    const int by = (id & 7) * (Bb * Hh / 8) + (id >> 3);   // bijective: 768 % 8 == 0
    const int y = by % Hh, b = by / Hh;
    const int x0 = blockIdx.y * (Ww / 2);
    float w9[9];
#pragma unroll
    for (int j = 0; j < 9; j++) w9[j] = wgt[c * 9 + j];
    const float bnA = BNC[c], bnB = BNC[384 + c];
    const float cb = cbias[c], sc = scale[c];
    const size_t base = (size_t)b * Nn * Dd;

    auto load3 = [&](int xx, float* col) {
        if (xx < 0 || xx >= Ww) { col[0] = col[1] = col[2] = 0.f; return; }
#pragma unroll
        for (int dy = 0; dy < 3; dy++) {
            int yy = y + dy - 1;
            if (yy < 0 || yy >= Hh) { col[dy] = 0.f; }
            else {
                int tok = yy * Ww + xx;
                col[dy] = geluf(bf2f(CF[base + (size_t)tok * Dd + c]) * bnA + bnB);
            }
        }
    };

    float A[3], B[3], C[3], T[3];
    load3(x0 - 1, A); load3(x0, B); load3(x0 + 1, C);
    float* xrow = X + base + ((size_t)y * Ww + x0) * Dd + c;
    for (int x = x0; x < x0 + Ww / 2; x++) {
        load3(x + 2, T);
        float acc = cb;
#pragma unroll
        for (int dy = 0; dy < 3; dy++)
            acc += w9[dy * 3] * A[dy] + w9[dy * 3 + 1] * B[dy] + w9[dy * 3 + 2] * C[dy];
        xrow[(size_t)(x - x0) * Dd] += sc * acc;
#pragma unroll
        for (int dy = 0; dy < 3; dy++) { A[dy] = B[dy]; B[dy] = C[dy]; C[dy] = T[dy]; }
    }
}

// ---------- host launch ----------
extern "C" void kernel_launch(void* const* d_in, const int* in_sizes, int n_in,
                              void* d_out, int out_size, void* d_ws, size_t ws_size,
                              hipStream_t stream) {
    const float* x     = (const float*)d_in[0];
    const float* ln1_g = (const float*)d_in[1];
    const float* ln1_b = (const float*)d_in[2];
    const float* w_qkv = (const float*)d_in[3];
    const float* temp  = (const float*)d_in[4];
    const float* w_out = (const float*)d_in[5];
    const float* b_out = (const float*)d_in[6];
    const float* s_att = (const float*)d_in[7];
    const float* lpi_g = (const float*)d_in[8];
    const float* lpi_b = (const float*)d_in[9];
    const float* c1w   = (const float*)d_in[10];
    const float* c1b   = (const float*)d_in[11];
    const float* bng   = (const float*)d_in[12];
    const float* bnb   = (const float*)d_in[13];
    const float* c2w   = (const float*)d_in[14];
    const float* c2b   = (const float*)d_in[15];
    const float* s_lpi = (const float*)d_in[16];
    const float* ff_g  = (const float*)d_in[17];
    const float* ff_b  = (const float*)d_in[18];
    const float* w1    = (const float*)d_in[19];
    const float* b1    = (const float*)d_in[20];
    const float* w2    = (const float*)d_in[21];
    const float* b2    = (const float*)d_in[22];
    const float* s_ff  = (const float*)d_in[23];

    float* X = (float*)d_out;  // residual stream lives in d_out (fp32)

    char* p = (char*)d_ws;
    auto carve = [&](size_t bytes) -> char* { char* r = p; p += (bytes + 255) / 256 * 256; return r; };
    u16*   BIG  = (u16*)  carve((size_t)NT * MF * 2);            // QKV / CF / FF1
    u16*   Hb   = (u16*)  carve((size_t)NT * Dd * 2);            // LN outputs
    float* SIM  = (float*)carve((size_t)Bb * NH * DHd * DHd * 4);
    float* SIMP = (float*)carve((size_t)NCH * Bb * NH * DHd * DHd * 4);
    float* INVN = (float*)carve((size_t)Bb * 768 * 4);
    float* QP   = (float*)carve((size_t)Bb * 9 * 768 * 4);
    float* LNP  = (float*)carve((size_t)3 * NT * 2 * 4);
    float* LNS  = (float*)carve((size_t)NT * 2 * 4);
    float* BNP  = (float*)carve((size_t)1536 * 768 * 4);
    float* BNQ  = (float*)carve((size_t)64 * 768 * 4);
    float* BNC  = (float*)carve((size_t)768 * 4);
    u16*   WQT  = (u16*)  carve((size_t)DEPTH * Dd * QC * 2);    // bf16 transposed weights [N][K]
    u16*   WOT  = (u16*)  carve((size_t)DEPTH * INNER * Dd * 2);
    u16*   W1T  = (u16*)  carve((size_t)DEPTH * Dd * MF * 2);
    u16*   W2T  = (u16*)  carve((size_t)DEPTH * MF * Dd * 2);
    u16*   AO   = BIG + (size_t)NT * QC;   // attention out aliases tail of BIG
    u16*   CF   = BIG;                     // conv1 bf16 out aliases BIG (QKV dead by then)

    k_trb<<<dim3(QC / 64, Dd / 64, DEPTH), 256, 0, stream>>>(w_qkv, WQT, Dd, QC);
    k_trb<<<dim3(Dd / 64, INNER / 64, DEPTH), 256, 0, stream>>>(w_out, WOT, INNER, Dd);
    k_trb<<<dim3(MF / 64, Dd / 64, DEPTH), 256, 0, stream>>>(w1, W1T, Dd, MF);
    k_trb<<<dim3(Dd / 64, MF / 64, DEPTH), 256, 0, stream>>>(w2, W2T, MF, Dd);

    k_copy<<<NT * Dd / 1024, 256, 0, stream>>>(x, X);
    for (int L = 0; L < DEPTH; L++) {
        // ---- XCA ----
        k_ln<<<NT / 4, 256, 0, stream>>>(X, ln1_g + L * Dd, ln1_b + L * Dd, Hb);
        k_mgemm<3><<<(QC / 128) * (NT / 256), 512, 0, stream>>>(Hb, WQT + (size_t)L * Dd * QC, Dd, QC,
                                                                nullptr, nullptr, nullptr, BIG, QP);
        k_nrm_fin<<<Bb * 768 / 256, 256, 0, stream>>>(QP, INVN);
        k_sim<<<dim3(Bb * NH, NCH), 256, 0, stream>>>(BIG, SIMP);
        k_smax<<<Bb * NH * DHd / 4, 256, 0, stream>>>(SIMP, SIM, INVN, temp + L * NH);
        k_av<<<dim3(Bb * NH, Nn / 256), 256, 0, stream>>>(BIG, SIM, AO);
        // attn-out GEMM also emits per-row LN partials (MODE 4) -> LNP
        k_mgemm<4><<<(Dd / 128) * (NT / 256), 512, 0, stream>>>(AO, WOT + (size_t)L * INNER * Dd, INNER, Dd,
                                                                b_out + L * Dd, s_att + L * Dd, X, nullptr, LNP);
        k_lnfin<<<NT / 256, 256, 0, stream>>>(LNP, LNS);
        // ---- LPI (fused) ----
        k_lpi1<<<dim3(Bb * Hh, 2), 384, 0, stream>>>(X, LNS, lpi_g + L * Dd, lpi_b + L * Dd,
                                                     c1w + (size_t)L * Dd * 9, c1b + L * Dd, CF, BNP);
        k_bnred1<<<64, 384, 0, stream>>>(BNP, BNQ);
        k_bnred2<<<1, 384, 0, stream>>>(BNQ, bng + L * Dd, bnb + L * Dd, BNC);
        k_lpi2<<<dim3(Bb * Hh, 2), 384, 0, stream>>>(CF, BNC, c2w + (size_t)L * Dd * 9, c2b + L * Dd,
                                                     s_lpi + L * Dd, X);
        // ---- FF ----
        k_ln<<<NT / 4, 256, 0, stream>>>(X, ff_g + L * Dd, ff_b + L * Dd, Hb);
        k_mgemm<1><<<(MF / 128) * (NT / 256), 512, 0, stream>>>(Hb, W1T + (size_t)L * Dd * MF, Dd, MF,
                                                                b1 + L * MF, nullptr, nullptr, BIG, nullptr);
        k_mgemm<2><<<(Dd / 128) * (NT / 256), 512, 0, stream>>>(BIG, W2T + (size_t)L * MF * Dd, MF, Dd,
                                                                b2 + L * Dd, s_ff + L * Dd, X, nullptr, nullptr);
    }
}